// Round 1
// baseline (132.922 us; speedup 1.0000x reference)
//
#include <hip/hip_runtime.h>

#define BATCH 8
#define NPTS 4096
#define TPB 256
#define NTILES (NPTS / TPB)      // 16
#define NCHUNKS 4
#define CHUNK (NPTS / NCHUNKS)   // 1024
#define BIGD 1e30f

// Stable top-2 update: strict < keeps the earlier-fed candidate on ties,
// matching jax.lax.top_k's lowest-index tie-break when candidates are fed
// in ascending index order.
__device__ __forceinline__ void top2_update(float d, int m,
                                            float& b1, int& i1,
                                            float& b2, int& i2) {
    bool c1 = d < b1;
    bool c2 = d < b2;
    float nb2 = c1 ? b1 : (c2 ? d : b2);
    int   ni2 = c1 ? i1 : (c2 ? m : i2);
    b1 = c1 ? d : b1;
    i1 = c1 ? m : i1;
    b2 = nb2;
    i2 = ni2;
}

// Stage `count` points (x,y,z,|p|^2) into LDS starting at global index mbase.
__device__ __forceinline__ void stage_points(const float* __restrict__ cb, int mbase,
                                             int count, float4* pts) {
    for (int p = (int)threadIdx.x; p < count; p += TPB) {
        float x = cb[(mbase + p) * 3 + 0];
        float y = cb[(mbase + p) * 3 + 1];
        float z = cb[(mbase + p) * 3 + 2];
        pts[p] = make_float4(x, y, z, x * x + y * y + z * z);
    }
}

// Scan `count` LDS-staged candidates, maintaining per-thread top-2.
// EXCLUDE_SELF: candidate global index == n must be skipped (distance 0).
template <bool EXCLUDE_SELF>
__device__ __forceinline__ void scan_chunk(const float4* __restrict__ pts, int count, int mbase,
                                           float xn, float yn, float zn, float sqn, int n,
                                           float& b1, int& i1, float& b2, int& i2) {
    for (int p = 0; p < count; p += 4) {
        float4 q0 = pts[p + 0];
        float4 q1 = pts[p + 1];
        float4 q2 = pts[p + 2];
        float4 q3 = pts[p + 3];
        // Expanded form matches the reference's sq[n]+sq[m]-2*inner ordering.
        float d0 = (sqn + q0.w) - 2.0f * (xn * q0.x + yn * q0.y + zn * q0.z);
        float d1 = (sqn + q1.w) - 2.0f * (xn * q1.x + yn * q1.y + zn * q1.z);
        float d2 = (sqn + q2.w) - 2.0f * (xn * q2.x + yn * q2.y + zn * q2.z);
        float d3 = (sqn + q3.w) - 2.0f * (xn * q3.x + yn * q3.y + zn * q3.z);
        int m0 = mbase + p;
        if (EXCLUDE_SELF) {
            // Rare: only groups containing some lane's own index.
            if (__any((unsigned)(n - m0) < 4u)) {
                if (n == m0 + 0) d0 = BIGD;
                if (n == m0 + 1) d1 = BIGD;
                if (n == m0 + 2) d2 = BIGD;
                if (n == m0 + 3) d3 = BIGD;
            }
        }
        float mn = fminf(fminf(d0, d1), fminf(d2, d3));
        // Wave vote: skip the select chain unless some lane improves its top-2.
        if (__any(mn < b2)) {
            top2_update(d0, m0 + 0, b1, i1, b2, i2);
            top2_update(d1, m0 + 1, b1, i1, b2, i2);
            top2_update(d2, m0 + 2, b1, i1, b2, i2);
            top2_update(d3, m0 + 3, b1, i1, b2, i2);
        }
    }
}

// Pass 1: each block = (n-tile of 256 queries, one m-chunk of 1024 candidates, batch b).
// Writes partial (d1, i1, d2, i2) per (query, chunk).
__global__ __launch_bounds__(TPB) void knn_partial_kernel(const float* __restrict__ coords,
                                                          float4* __restrict__ partial) {
    __shared__ float4 pts[CHUNK];  // 16 KB
    const int tile  = blockIdx.x;
    const int chunk = blockIdx.y;
    const int b     = blockIdx.z;
    const float* cb = coords + (size_t)b * NPTS * 3;
    const int mbase = chunk * CHUNK;

    stage_points(cb, mbase, CHUNK, pts);

    const int n = tile * TPB + (int)threadIdx.x;
    const float xn = cb[n * 3 + 0];
    const float yn = cb[n * 3 + 1];
    const float zn = cb[n * 3 + 2];
    const float sqn = xn * xn + yn * yn + zn * zn;
    __syncthreads();

    float b1 = BIGD, b2 = BIGD;
    int i1 = 0, i2 = 0;
    // Block-uniform: does this block's n-tile fall inside its m-chunk?
    if ((tile * TPB) / CHUNK == chunk) {
        scan_chunk<true>(pts, CHUNK, mbase, xn, yn, zn, sqn, n, b1, i1, b2, i2);
    } else {
        scan_chunk<false>(pts, CHUNK, mbase, xn, yn, zn, sqn, n, b1, i1, b2, i2);
    }

    const int q = b * NPTS + n;
    partial[(size_t)q * NCHUNKS + chunk] =
        make_float4(b1, __int_as_float(i1), b2, __int_as_float(i2));
}

// Pass 2: merge the NCHUNKS partials per query (fed in ascending-index order
// for stability), gather neighbor coords, write all four outputs.
__global__ __launch_bounds__(TPB) void knn_merge_kernel(const float* __restrict__ coords,
                                                        const float4* __restrict__ partial,
                                                        float* __restrict__ out) {
    const int q = blockIdx.x * TPB + (int)threadIdx.x;  // 0..BATCH*NPTS-1
    const int b = q >> 12;                              // / NPTS
    float b1 = BIGD, b2 = BIGD;
    int i1 = 0, i2 = 0;
#pragma unroll
    for (int c = 0; c < NCHUNKS; ++c) {
        float4 pc = partial[(size_t)q * NCHUNKS + c];
        top2_update(pc.x, __float_as_int(pc.y), b1, i1, b2, i2);
        top2_update(pc.z, __float_as_int(pc.w), b1, i1, b2, i2);
    }
    const float* cb = coords + (size_t)b * NPTS * 3;
    float* A  = out;
    float* C  = out + (size_t)BATCH * NPTS * 3;
    float* I1 = out + (size_t)2 * BATCH * NPTS * 3;
    float* I2 = I1 + (size_t)BATCH * NPTS;

    A[(size_t)q * 3 + 0] = cb[i1 * 3 + 0];
    A[(size_t)q * 3 + 1] = cb[i1 * 3 + 1];
    A[(size_t)q * 3 + 2] = cb[i1 * 3 + 2];
    C[(size_t)q * 3 + 0] = cb[i2 * 3 + 0];
    C[(size_t)q * 3 + 1] = cb[i2 * 3 + 1];
    C[(size_t)q * 3 + 2] = cb[i2 * 3 + 2];
    I1[q] = (float)i1;
    I2[q] = (float)i2;
}

// Fallback (ws too small): one kernel does the full scan with all 4096 points
// in 64 KB LDS and writes outputs directly (gathers from LDS).
__global__ __launch_bounds__(TPB) void knn_full_kernel(const float* __restrict__ coords,
                                                       float* __restrict__ out) {
    __shared__ float4 pts[NPTS];  // 64 KB
    const int tile = blockIdx.x;
    const int b    = blockIdx.y;
    const float* cb = coords + (size_t)b * NPTS * 3;

    stage_points(cb, 0, NPTS, pts);

    const int n = tile * TPB + (int)threadIdx.x;
    const float xn = cb[n * 3 + 0];
    const float yn = cb[n * 3 + 1];
    const float zn = cb[n * 3 + 2];
    const float sqn = xn * xn + yn * yn + zn * zn;
    __syncthreads();

    float b1 = BIGD, b2 = BIGD;
    int i1 = 0, i2 = 0;
    scan_chunk<true>(pts, NPTS, 0, xn, yn, zn, sqn, n, b1, i1, b2, i2);

    const int q = b * NPTS + n;
    float4 p1 = pts[i1];
    float4 p2 = pts[i2];
    float* A  = out;
    float* C  = out + (size_t)BATCH * NPTS * 3;
    float* I1 = out + (size_t)2 * BATCH * NPTS * 3;
    float* I2 = I1 + (size_t)BATCH * NPTS;

    A[(size_t)q * 3 + 0] = p1.x;
    A[(size_t)q * 3 + 1] = p1.y;
    A[(size_t)q * 3 + 2] = p1.z;
    C[(size_t)q * 3 + 0] = p2.x;
    C[(size_t)q * 3 + 1] = p2.y;
    C[(size_t)q * 3 + 2] = p2.z;
    I1[q] = (float)i1;
    I2[q] = (float)i2;
}

extern "C" void kernel_launch(void* const* d_in, const int* in_sizes, int n_in,
                              void* d_out, int out_size, void* d_ws, size_t ws_size,
                              hipStream_t stream) {
    const float* coords = (const float*)d_in[0];
    // d_in[1] (mask) is all-true in the reference and unused by it — ignored.
    float* out = (float*)d_out;

    const size_t need = (size_t)BATCH * NPTS * NCHUNKS * sizeof(float4);  // 2 MB
    if (ws_size >= need) {
        float4* partial = (float4*)d_ws;
        dim3 g1(NTILES, NCHUNKS, BATCH);
        hipLaunchKernelGGL(knn_partial_kernel, g1, dim3(TPB), 0, stream, coords, partial);
        hipLaunchKernelGGL(knn_merge_kernel, dim3((BATCH * NPTS) / TPB), dim3(TPB), 0, stream,
                           coords, partial, out);
    } else {
        dim3 g(NTILES, BATCH);
        hipLaunchKernelGGL(knn_full_kernel, g, dim3(TPB), 0, stream, coords, out);
    }
}

// Round 3
// 109.662 us; speedup vs baseline: 1.2121x; 1.2121x over previous
//
#include <hip/hip_runtime.h>

#define BATCH 8
#define NPTS 4096
#define TOTQ (BATCH * NPTS)
#define TPB 256
#define BIGD 1e30f

// Branchless stable top-2 (min). Invariant b1 <= b2. Strict < keeps the
// earlier-fed candidate on exact ties (== jax.lax.top_k lowest-index rule
// when fed in ascending index order).
__device__ __forceinline__ void top2min(float k, int m,
                                        float& b1, int& i1,
                                        float& b2, int& i2) {
    bool c1 = k < b1;
    bool c2 = k < b2;
    int ni2 = c2 ? m : i2;
    i2 = c1 ? i1 : ni2;
    i1 = c1 ? m : i1;
    b2 = fminf(fmaxf(k, b1), b2);   // median(b1,b2,k) given b1<=b2 -> v_med3
    b1 = fminf(k, b1);
}

// Inner scan over one LDS-staged chunk. EXC: this block's query tile overlaps
// its candidate chunk, so self (m==n) must be masked per pair. Key
// k = |p_m|^2 - 2*dot(p_n,p_m) = d^2 - |p_n|^2: same ordering as d, 3 FMAs.
template <int CHUNKSZ, int Q, bool EXC>
__device__ __forceinline__ void scan_loop(const float4* __restrict__ pts, int mbase,
                                          const int* nq,
                                          const float* xn, const float* yn, const float* zn,
                                          float* b1, int* i1, float* b2, int* i2) {
    for (int p = 0; p < CHUNKSZ; p += 4) {
        float4 c0 = pts[p + 0];
        float4 c1 = pts[p + 1];
        float4 c2 = pts[p + 2];
        float4 c3 = pts[p + 3];
        const int m0 = mbase + p;
#pragma unroll
        for (int q = 0; q < Q; ++q) {
            float k0 = fmaf(c0.x, xn[q], fmaf(c0.y, yn[q], fmaf(c0.z, zn[q], c0.w)));
            float k1 = fmaf(c1.x, xn[q], fmaf(c1.y, yn[q], fmaf(c1.z, zn[q], c1.w)));
            float k2 = fmaf(c2.x, xn[q], fmaf(c2.y, yn[q], fmaf(c2.z, zn[q], c2.w)));
            float k3 = fmaf(c3.x, xn[q], fmaf(c3.y, yn[q], fmaf(c3.z, zn[q], c3.w)));
            if (EXC) {
                k0 = (m0 + 0 == nq[q]) ? BIGD : k0;
                k1 = (m0 + 1 == nq[q]) ? BIGD : k1;
                k2 = (m0 + 2 == nq[q]) ? BIGD : k2;
                k3 = (m0 + 3 == nq[q]) ? BIGD : k3;
            }
            top2min(k0, m0 + 0, b1[q], i1[q], b2[q], i2[q]);
            top2min(k1, m0 + 1, b1[q], i1[q], b2[q], i2[q]);
            top2min(k2, m0 + 2, b1[q], i1[q], b2[q], i2[q]);
            top2min(k3, m0 + 3, b1[q], i1[q], b2[q], i2[q]);
        }
    }
}

// Pass 1: block = (query tile of TPB*Q, candidate chunk of NPTS/NCHUNKS, batch).
// Self is excluded during the scan (block-uniform overlap test picks the EXC
// instantiation), so each chunk partial is a true non-self top-2.
template <int NCHUNKS, int Q>
__global__ __launch_bounds__(TPB) void knn_scan(const float* __restrict__ coords,
                                                float4* __restrict__ partial) {
    constexpr int CHUNKSZ = NPTS / NCHUNKS;
    __shared__ float4 pts[CHUNKSZ];
    const int tid   = (int)threadIdx.x;
    const int tile  = blockIdx.x;
    const int chunk = blockIdx.y;
    const int b     = blockIdx.z;
    const float* cb = coords + (size_t)b * NPTS * 3;
    const int mbase = chunk * CHUNKSZ;

    // Stage (-2x, -2y, -2z, |p|^2)
    for (int p = tid; p < CHUNKSZ; p += TPB) {
        float x = cb[(mbase + p) * 3 + 0];
        float y = cb[(mbase + p) * 3 + 1];
        float z = cb[(mbase + p) * 3 + 2];
        pts[p] = make_float4(-2.0f * x, -2.0f * y, -2.0f * z, x * x + y * y + z * z);
    }

    const int qbase = tile * (TPB * Q);
    int nq[Q];
    float xn[Q], yn[Q], zn[Q], b1[Q], b2[Q];
    int i1[Q], i2[Q];
#pragma unroll
    for (int q = 0; q < Q; ++q) {
        int n = qbase + q * TPB + tid;
        nq[q] = n;
        xn[q] = cb[n * 3 + 0];
        yn[q] = cb[n * 3 + 1];
        zn[q] = cb[n * 3 + 2];
        b1[q] = BIGD; b2[q] = BIGD; i1[q] = 0; i2[q] = 0;
    }
    __syncthreads();

    // Block-uniform: does this block's query tile overlap its candidate chunk?
    const int qend = qbase + TPB * Q;
    const int mend = mbase + CHUNKSZ;
    if (mbase < qend && qbase < mend) {
        scan_loop<CHUNKSZ, Q, true >(pts, mbase, nq, xn, yn, zn, b1, i1, b2, i2);
    } else {
        scan_loop<CHUNKSZ, Q, false>(pts, mbase, nq, xn, yn, zn, b1, i1, b2, i2);
    }

    // Partial layout [chunk][global query] -> both passes fully coalesced.
#pragma unroll
    for (int q = 0; q < Q; ++q) {
        int n = qbase + q * TPB + tid;
        partial[(size_t)chunk * TOTQ + (size_t)b * NPTS + n] =
            make_float4(b1[q], __int_as_float(i1[q]), b2[q], __int_as_float(i2[q]));
    }
}

// Pass 2: merge NCHUNKS partials per query (ascending chunk = ascending index
// = stable), then gather neighbor coords and write all four outputs.
template <int NCHUNKS>
__global__ __launch_bounds__(TPB) void knn_merge(const float* __restrict__ coords,
                                                 const float4* __restrict__ partial,
                                                 float* __restrict__ out) {
    const int q = blockIdx.x * TPB + (int)threadIdx.x;  // 0..TOTQ-1
    const int b = q >> 12;                              // / NPTS
    float b1 = BIGD, b2 = BIGD;
    int i1 = 0, i2 = 0;
#pragma unroll
    for (int c = 0; c < NCHUNKS; ++c) {
        float4 pc = partial[(size_t)c * TOTQ + q];
        top2min(pc.x, __float_as_int(pc.y), b1, i1, b2, i2);
        top2min(pc.z, __float_as_int(pc.w), b1, i1, b2, i2);
    }
    const float* cb = coords + (size_t)b * NPTS * 3;
    float* A  = out;
    float* C  = out + (size_t)TOTQ * 3;
    float* I1 = out + (size_t)2 * TOTQ * 3;
    float* I2 = I1 + (size_t)TOTQ;

    A[(size_t)q * 3 + 0] = cb[i1 * 3 + 0];
    A[(size_t)q * 3 + 1] = cb[i1 * 3 + 1];
    A[(size_t)q * 3 + 2] = cb[i1 * 3 + 2];
    C[(size_t)q * 3 + 0] = cb[i2 * 3 + 0];
    C[(size_t)q * 3 + 1] = cb[i2 * 3 + 1];
    C[(size_t)q * 3 + 2] = cb[i2 * 3 + 2];
    I1[q] = (float)i1;
    I2[q] = (float)i2;
}

// Fallback if ws can't hold even the 2 MB partial buffer: monolithic kernel,
// all 4096 candidates in 64 KB LDS, per-pair branchless self-exclusion.
__global__ __launch_bounds__(TPB) void knn_full(const float* __restrict__ coords,
                                                float* __restrict__ out) {
    __shared__ float4 pts[NPTS];  // 64 KB
    const int tid  = (int)threadIdx.x;
    const int tile = blockIdx.x;
    const int b    = blockIdx.y;
    const float* cb = coords + (size_t)b * NPTS * 3;

    for (int p = tid; p < NPTS; p += TPB) {
        float x = cb[p * 3 + 0];
        float y = cb[p * 3 + 1];
        float z = cb[p * 3 + 2];
        pts[p] = make_float4(-2.0f * x, -2.0f * y, -2.0f * z, x * x + y * y + z * z);
    }
    const int n = tile * TPB + tid;
    const float xn = cb[n * 3 + 0];
    const float yn = cb[n * 3 + 1];
    const float zn = cb[n * 3 + 2];
    __syncthreads();

    float b1 = BIGD, b2 = BIGD;
    int i1 = 0, i2 = 0;
    for (int p = 0; p < NPTS; p += 4) {
#pragma unroll
        for (int j = 0; j < 4; ++j) {
            float4 c = pts[p + j];
            float k = fmaf(c.x, xn, fmaf(c.y, yn, fmaf(c.z, zn, c.w)));
            k = (p + j == n) ? BIGD : k;
            top2min(k, p + j, b1, i1, b2, i2);
        }
    }

    const int q = b * NPTS + n;
    float* A  = out;
    float* C  = out + (size_t)TOTQ * 3;
    float* I1 = out + (size_t)2 * TOTQ * 3;
    float* I2 = I1 + (size_t)TOTQ;
    float4 p1 = pts[i1];
    float4 p2 = pts[i2];
    A[(size_t)q * 3 + 0] = -0.5f * p1.x;
    A[(size_t)q * 3 + 1] = -0.5f * p1.y;
    A[(size_t)q * 3 + 2] = -0.5f * p1.z;
    C[(size_t)q * 3 + 0] = -0.5f * p2.x;
    C[(size_t)q * 3 + 1] = -0.5f * p2.y;
    C[(size_t)q * 3 + 2] = -0.5f * p2.z;
    I1[q] = (float)i1;
    I2[q] = (float)i2;
}

extern "C" void kernel_launch(void* const* d_in, const int* in_sizes, int n_in,
                              void* d_out, int out_size, void* d_ws, size_t ws_size,
                              hipStream_t stream) {
    const float* coords = (const float*)d_in[0];
    float* out = (float*)d_out;
    float4* partial = (float4*)d_ws;
    const size_t chunk_bytes = (size_t)TOTQ * sizeof(float4);  // 512 KB per chunk

    if (ws_size >= 16 * chunk_bytes) {          // 8 MB: NCHUNKS=16, Q=4
        hipLaunchKernelGGL((knn_scan<16, 4>), dim3(4, 16, BATCH), dim3(TPB), 0, stream,
                           coords, partial);
        hipLaunchKernelGGL((knn_merge<16>), dim3(TOTQ / TPB), dim3(TPB), 0, stream,
                           coords, partial, out);
    } else if (ws_size >= 8 * chunk_bytes) {    // 4 MB: NCHUNKS=8, Q=2
        hipLaunchKernelGGL((knn_scan<8, 2>), dim3(8, 8, BATCH), dim3(TPB), 0, stream,
                           coords, partial);
        hipLaunchKernelGGL((knn_merge<8>), dim3(TOTQ / TPB), dim3(TPB), 0, stream,
                           coords, partial, out);
    } else if (ws_size >= 4 * chunk_bytes) {    // 2 MB: NCHUNKS=4, Q=1
        hipLaunchKernelGGL((knn_scan<4, 1>), dim3(16, 4, BATCH), dim3(TPB), 0, stream,
                           coords, partial);
        hipLaunchKernelGGL((knn_merge<4>), dim3(TOTQ / TPB), dim3(TPB), 0, stream,
                           coords, partial, out);
    } else {
        hipLaunchKernelGGL(knn_full, dim3(NPTS / TPB, BATCH), dim3(TPB), 0, stream,
                           coords, out);
    }
}

// Round 4
// 107.048 us; speedup vs baseline: 1.2417x; 1.0244x over previous
//
#include <hip/hip_runtime.h>

#define BATCH 8
#define NPTS 4096
#define TOTQ (BATCH * NPTS)
#define TPB 256
#define BIGD 1e30f

// Branchless stable top-2 (min). Invariant b1 <= b2. Strict < keeps the
// earlier-fed candidate on exact ties (== jax.lax.top_k lowest-index rule
// when fed in ascending index order).
__device__ __forceinline__ void top2min(float k, int m,
                                        float& b1, int& i1,
                                        float& b2, int& i2) {
    bool c1 = k < b1;
    bool c2 = k < b2;
    int ni2 = c2 ? m : i2;
    i2 = c1 ? i1 : ni2;
    i1 = c1 ? m : i1;
    b2 = fminf(fmaxf(k, b1), b2);   // median(b1,b2,k) given b1<=b2 -> v_med3
    b1 = fminf(k, b1);
}

// Inner scan: 8 candidates are loaded into a register block up front (visible
// prefetch window for the scheduler), then processed for all Q queries.
// EXC: this block's query tile overlaps its candidate chunk -> mask self.
// Key k = |p_m|^2 - 2*dot(p_n,p_m) = d^2 - |p_n|^2: same ordering as d, 3 FMAs.
template <int CHUNKSZ, int Q, bool EXC>
__device__ __forceinline__ void scan_loop(const float4* __restrict__ pts, int mbase,
                                          const int* nq,
                                          const float* xn, const float* yn, const float* zn,
                                          float* b1, int* i1, float* b2, int* i2) {
    for (int p = 0; p < CHUNKSZ; p += 8) {
        float4 c[8];
#pragma unroll
        for (int j = 0; j < 8; ++j) c[j] = pts[p + j];
#pragma unroll
        for (int j = 0; j < 8; ++j) {
            const int m = mbase + p + j;
#pragma unroll
            for (int q = 0; q < Q; ++q) {
                float k = fmaf(c[j].x, xn[q], fmaf(c[j].y, yn[q], fmaf(c[j].z, zn[q], c[j].w)));
                if (EXC) k = (m == nq[q]) ? BIGD : k;
                top2min(k, m, b1[q], i1[q], b2[q], i2[q]);
            }
        }
    }
}

// Pass 1: block = (query tile of TPB*Q, candidate chunk of NPTS/NCHUNKS, batch).
// Self is excluded during the scan (block-uniform overlap test picks the EXC
// instantiation), so each chunk partial is a true non-self top-2.
template <int NCHUNKS, int Q>
__global__ __launch_bounds__(TPB) void knn_scan(const float* __restrict__ coords,
                                                float4* __restrict__ partial) {
    constexpr int CHUNKSZ = NPTS / NCHUNKS;
    __shared__ float4 pts[CHUNKSZ];
    const int tid   = (int)threadIdx.x;
    const int tile  = blockIdx.x;
    const int chunk = blockIdx.y;
    const int b     = blockIdx.z;
    const float* cb = coords + (size_t)b * NPTS * 3;
    const int mbase = chunk * CHUNKSZ;

    // Stage (-2x, -2y, -2z, |p|^2)
    for (int p = tid; p < CHUNKSZ; p += TPB) {
        float x = cb[(mbase + p) * 3 + 0];
        float y = cb[(mbase + p) * 3 + 1];
        float z = cb[(mbase + p) * 3 + 2];
        pts[p] = make_float4(-2.0f * x, -2.0f * y, -2.0f * z, x * x + y * y + z * z);
    }

    const int qbase = tile * (TPB * Q);
    int nq[Q];
    float xn[Q], yn[Q], zn[Q], b1[Q], b2[Q];
    int i1[Q], i2[Q];
#pragma unroll
    for (int q = 0; q < Q; ++q) {
        int n = qbase + q * TPB + tid;
        nq[q] = n;
        xn[q] = cb[n * 3 + 0];
        yn[q] = cb[n * 3 + 1];
        zn[q] = cb[n * 3 + 2];
        b1[q] = BIGD; b2[q] = BIGD; i1[q] = 0; i2[q] = 0;
    }
    __syncthreads();

    // Block-uniform: does this block's query tile overlap its candidate chunk?
    const int qend = qbase + TPB * Q;
    const int mend = mbase + CHUNKSZ;
    if (mbase < qend && qbase < mend) {
        scan_loop<CHUNKSZ, Q, true >(pts, mbase, nq, xn, yn, zn, b1, i1, b2, i2);
    } else {
        scan_loop<CHUNKSZ, Q, false>(pts, mbase, nq, xn, yn, zn, b1, i1, b2, i2);
    }

    // Partial layout [chunk][global query] -> both passes fully coalesced.
#pragma unroll
    for (int q = 0; q < Q; ++q) {
        int n = qbase + q * TPB + tid;
        partial[(size_t)chunk * TOTQ + (size_t)b * NPTS + n] =
            make_float4(b1[q], __int_as_float(i1[q]), b2[q], __int_as_float(i2[q]));
    }
}

// Pass 2: merge NCHUNKS partials per query (ascending chunk = ascending index
// = stable), then gather neighbor coords and write all four outputs.
template <int NCHUNKS>
__global__ __launch_bounds__(TPB) void knn_merge(const float* __restrict__ coords,
                                                 const float4* __restrict__ partial,
                                                 float* __restrict__ out) {
    const int q = blockIdx.x * TPB + (int)threadIdx.x;  // 0..TOTQ-1
    const int b = q >> 12;                              // / NPTS
    float b1 = BIGD, b2 = BIGD;
    int i1 = 0, i2 = 0;
#pragma unroll
    for (int c = 0; c < NCHUNKS; ++c) {
        float4 pc = partial[(size_t)c * TOTQ + q];
        top2min(pc.x, __float_as_int(pc.y), b1, i1, b2, i2);
        top2min(pc.z, __float_as_int(pc.w), b1, i1, b2, i2);
    }
    const float* cb = coords + (size_t)b * NPTS * 3;
    float* A  = out;
    float* C  = out + (size_t)TOTQ * 3;
    float* I1 = out + (size_t)2 * TOTQ * 3;
    float* I2 = I1 + (size_t)TOTQ;

    A[(size_t)q * 3 + 0] = cb[i1 * 3 + 0];
    A[(size_t)q * 3 + 1] = cb[i1 * 3 + 1];
    A[(size_t)q * 3 + 2] = cb[i1 * 3 + 2];
    C[(size_t)q * 3 + 0] = cb[i2 * 3 + 0];
    C[(size_t)q * 3 + 1] = cb[i2 * 3 + 1];
    C[(size_t)q * 3 + 2] = cb[i2 * 3 + 2];
    I1[q] = (float)i1;
    I2[q] = (float)i2;
}

// Fallback if ws can't hold even the 2 MB partial buffer: monolithic kernel.
__global__ __launch_bounds__(TPB) void knn_full(const float* __restrict__ coords,
                                                float* __restrict__ out) {
    __shared__ float4 pts[NPTS];  // 64 KB
    const int tid  = (int)threadIdx.x;
    const int tile = blockIdx.x;
    const int b    = blockIdx.y;
    const float* cb = coords + (size_t)b * NPTS * 3;

    for (int p = tid; p < NPTS; p += TPB) {
        float x = cb[p * 3 + 0];
        float y = cb[p * 3 + 1];
        float z = cb[p * 3 + 2];
        pts[p] = make_float4(-2.0f * x, -2.0f * y, -2.0f * z, x * x + y * y + z * z);
    }
    const int n = tile * TPB + tid;
    const float xn = cb[n * 3 + 0];
    const float yn = cb[n * 3 + 1];
    const float zn = cb[n * 3 + 2];
    __syncthreads();

    float b1 = BIGD, b2 = BIGD;
    int i1 = 0, i2 = 0;
    for (int p = 0; p < NPTS; p += 4) {
#pragma unroll
        for (int j = 0; j < 4; ++j) {
            float4 c = pts[p + j];
            float k = fmaf(c.x, xn, fmaf(c.y, yn, fmaf(c.z, zn, c.w)));
            k = (p + j == n) ? BIGD : k;
            top2min(k, p + j, b1, i1, b2, i2);
        }
    }

    const int q = b * NPTS + n;
    float* A  = out;
    float* C  = out + (size_t)TOTQ * 3;
    float* I1 = out + (size_t)2 * TOTQ * 3;
    float* I2 = I1 + (size_t)TOTQ;
    float4 p1 = pts[i1];
    float4 p2 = pts[i2];
    A[(size_t)q * 3 + 0] = -0.5f * p1.x;
    A[(size_t)q * 3 + 1] = -0.5f * p1.y;
    A[(size_t)q * 3 + 2] = -0.5f * p1.z;
    C[(size_t)q * 3 + 0] = -0.5f * p2.x;
    C[(size_t)q * 3 + 1] = -0.5f * p2.y;
    C[(size_t)q * 3 + 2] = -0.5f * p2.z;
    I1[q] = (float)i1;
    I2[q] = (float)i2;
}

extern "C" void kernel_launch(void* const* d_in, const int* in_sizes, int n_in,
                              void* d_out, int out_size, void* d_ws, size_t ws_size,
                              hipStream_t stream) {
    const float* coords = (const float*)d_in[0];
    float* out = (float*)d_out;
    float4* partial = (float4*)d_ws;
    const size_t chunk_bytes = (size_t)TOTQ * sizeof(float4);  // 512 KB per chunk

    if (ws_size >= 32 * chunk_bytes) {          // 16 MB: NCHUNKS=32, Q=4 -> 1024 blocks
        hipLaunchKernelGGL((knn_scan<32, 4>), dim3(4, 32, BATCH), dim3(TPB), 0, stream,
                           coords, partial);
        hipLaunchKernelGGL((knn_merge<32>), dim3(TOTQ / TPB), dim3(TPB), 0, stream,
                           coords, partial, out);
    } else if (ws_size >= 16 * chunk_bytes) {   // 8 MB: NCHUNKS=16, Q=4
        hipLaunchKernelGGL((knn_scan<16, 4>), dim3(4, 16, BATCH), dim3(TPB), 0, stream,
                           coords, partial);
        hipLaunchKernelGGL((knn_merge<16>), dim3(TOTQ / TPB), dim3(TPB), 0, stream,
                           coords, partial, out);
    } else if (ws_size >= 8 * chunk_bytes) {    // 4 MB: NCHUNKS=8, Q=2
        hipLaunchKernelGGL((knn_scan<8, 2>), dim3(8, 8, BATCH), dim3(TPB), 0, stream,
                           coords, partial);
        hipLaunchKernelGGL((knn_merge<8>), dim3(TOTQ / TPB), dim3(TPB), 0, stream,
                           coords, partial, out);
    } else if (ws_size >= 4 * chunk_bytes) {    // 2 MB: NCHUNKS=4, Q=1
        hipLaunchKernelGGL((knn_scan<4, 1>), dim3(16, 4, BATCH), dim3(TPB), 0, stream,
                           coords, partial);
        hipLaunchKernelGGL((knn_merge<4>), dim3(TOTQ / TPB), dim3(TPB), 0, stream,
                           coords, partial, out);
    } else {
        hipLaunchKernelGGL(knn_full, dim3(NPTS / TPB, BATCH), dim3(TPB), 0, stream,
                           coords, out);
    }
}